// Round 13
// baseline (189.720 us; speedup 1.0000x reference)
//
#include <hip/hip_runtime.h>
#include <stdint.h>

#define BB  2
#define NN  100000
#define MM  16384
#define SS  3
#define EE  262144
#define CC  32
#define HH  64
#define TPB 256
#define WPB 4            // waves per block
#define WIN 128          // edges per window
#define NWIN 4           // windows per wave (12288 / (768*4))
#define ACCR 12          // accumulator rows per wave

typedef _Float16 f16;
typedef _Float16 f16x2 __attribute__((ext_vector_type(2)));
typedef _Float16 f16x4 __attribute__((ext_vector_type(4)));
typedef _Float16 f16x8 __attribute__((ext_vector_type(8)));
typedef float    f32x4 __attribute__((ext_vector_type(4)));
typedef int      i32x4 __attribute__((ext_vector_type(4)));

// gelu = x * (1 - 1/(1 + 2^(K1*x + K3*x^3)))  (exact tanh-gelu reformulation)
__device__ __forceinline__ float gelu_tanh(float x){
  float u = x * fmaf(0.10294232f, x * x, 2.30218762f);
  float e = exp2f(u);
  float r = __builtin_amdgcn_rcpf(e + 1.0f);
  return fmaf(-x, r, x);
}

__device__ __forceinline__ int pk2(float a, float b){
  f16x2 h = { (f16)a, (f16)b };
  return __builtin_bit_cast(int, h);
}

// ---- pack: f16 W1(+b1, K=8 pad), W2, W3, W_lift(+b_lift at k=4..7) ----
extern "C" __global__ void magno_pack(const float* __restrict__ W1, const float* __restrict__ b1,
                                      const float* __restrict__ W2, const float* __restrict__ W3,
                                      const float* __restrict__ W_lift, const float* __restrict__ b_lift,
                                      f16* __restrict__ W1p, f16* __restrict__ W2h,
                                      f16* __restrict__ W3h, f16* __restrict__ WLp){
  int i = blockIdx.x * blockDim.x + threadIdx.x;
  if (i < HH * HH) W2h[i] = (f16)W2[i];
  if (i < CC * HH) W3h[i] = (f16)W3[i];
  if (i < HH * 8){
    int j = i >> 3, k = i & 7;
    float v = (k < 4) ? W1[j * 4 + k] : (k == 4 ? b1[j] : 0.f);
    W1p[i] = (f16)v;
  }
  if (i < CC * 8){
    int c = i >> 3, k = i & 7;
    float v = (k == 4) ? b_lift[c] : (k >= 5 ? W_lift[c * 3 + (k - 5)] : 0.f);
    WLp[i] = (f16)v;
  }
}

// ---- coef[b,s,m] = softmax_s(scaleMLP(lat_m)) / max(cnt,1) ----
extern "C" __global__ void magno_coef(const float* __restrict__ lat, const int* __restrict__ row_idx,
                                      const float* __restrict__ Ws1, const float* __restrict__ bs1,
                                      const float* __restrict__ Ws2, const float* __restrict__ bs2,
                                      float* __restrict__ coefw){
  int idx = blockIdx.x * blockDim.x + threadIdx.x;
  if (idx >= BB * SS * MM) return;
  int m = idx % MM, s = (idx / MM) % SS, b = idx / (SS * MM);
  const int* rows = row_idx + (size_t)(b * SS + s) * EE;
  int lo = 0, hi = EE;
  while (lo < hi){ int mid = (lo + hi) >> 1; if (rows[mid] < m) lo = mid + 1; else hi = mid; }
  int l0 = lo; hi = EE;
  while (lo < hi){ int mid = (lo + hi) >> 1; if (rows[mid] < m + 1) lo = mid + 1; else hi = mid; }
  float cnt = (float)(lo - l0);
  float la = lat[m * 2 + 0], lb = lat[m * 2 + 1];
  float t[16];
  #pragma unroll
  for (int i = 0; i < 16; i++)
    t[i] = fmaxf(fmaf(la, Ws1[i * 2 + 0], fmaf(lb, Ws1[i * 2 + 1], bs1[i])), 0.f);
  float a0 = bs2[0], a1 = bs2[1], a2 = bs2[2];
  #pragma unroll
  for (int i = 0; i < 16; i++){
    a0 = fmaf(t[i], Ws2[i], a0); a1 = fmaf(t[i], Ws2[16 + i], a1); a2 = fmaf(t[i], Ws2[32 + i], a2);
  }
  float mx = fmaxf(a0, fmaxf(a1, a2));
  float e0 = __expf(a0 - mx), e1 = __expf(a1 - mx), e2 = __expf(a2 - mx);
  float inv = 1.f / (e0 + e1 + e2);
  float sw = (s == 0 ? e0 : (s == 1 ? e1 : e2)) * inv;
  coefw[idx] = sw / fmaxf(cnt, 1.f);
}

extern "C" __global__ void __launch_bounds__(TPB, 2)
magno_main(const float* __restrict__ x_coord,
           const float* __restrict__ pndata,
           const float* __restrict__ lat,
           const int* __restrict__ nbr_idx,
           const int* __restrict__ row_idx,
           const float* __restrict__ b2,
           const float* __restrict__ b3,
           const f16* __restrict__ W1p,
           const f16* __restrict__ W2h,
           const f16* __restrict__ W3h,
           const f16* __restrict__ WLp,
           const float* __restrict__ coefw,
           float* __restrict__ out)
{
  __shared__ __align__(16) f16   hbuf[WPB][64 * 64];   // TWO 32-edge pipeline tiles   32KB
  __shared__ ushort rloc[WPB][2][64];                  // local row per edge            1KB
  __shared__ float  accs[WPB][ACCR * CC];              // per-wave accumulators         6KB
  __shared__ __align__(16) f16   w2lds[HH * HH];       // W2 frags (XOR-swizzled)       8KB
  __shared__ __align__(16) f16   w3lds[CC * HH];       // W3 frags (XOR-swizzled)       4KB
  // total 52224 B -> 3 blocks/CU

  const int tid  = threadIdx.x;
  const int wv   = tid >> 6;
  const int lane = tid & 63;
  const int g    = lane >> 4;
  const int n    = lane & 15;
  const int wslot = blockIdx.x * WPB + wv;

  const f16x8 zf = {0,0,0,0,0,0,0,0};
  const f32x4 z4 = {0.f,0.f,0.f,0.f};

  // ---- stage W2/W3 into block LDS with XOR swizzle (col ^= (row&7)<<3, f16 units) ----
  for (int c = tid; c < 512; c += TPB){
    int row = c >> 3, cb = (c & 7) * 8;
    f16x8 v = *(const f16x8*)(W2h + row * HH + cb);
    *(f16x8*)(w2lds + row * HH + (cb ^ ((row & 7) << 3))) = v;
  }
  for (int c = tid; c < 256; c += TPB){
    int row = c >> 3, cb = (c & 7) * 8;
    f16x8 v = *(const f16x8*)(W3h + row * HH + cb);
    *(f16x8*)(w3lds + row * HH + (cb ^ ((row & 7) << 3))) = v;
  }

  // ---- register-resident small weights ----
  f16x8 w1f[4], wlf[2];
  #pragma unroll
  for (int nt = 0; nt < 4; nt++){
    f16x8 v = *(const f16x8*)(W1p + (16 * nt + n) * 8);
    w1f[nt] = (g == 0) ? v : zf;
  }
  #pragma unroll
  for (int nt = 0; nt < 2; nt++){
    f16x8 v = *(const f16x8*)(WLp + (16 * nt + n) * 8);
    wlf[nt] = (g == 0) ? v : zf;
  }
  float4 b2vv[4];
  #pragma unroll
  for (int jt = 0; jt < 4; jt++) b2vv[jt] = *(const float4*)(b2 + 16 * jt + 4 * g);
  float b3v[2];
  #pragma unroll
  for (int nt = 0; nt < 2; nt++) b3v[nt] = b3[16 * nt + n];

  // bpermute byte-indices for the lane->fragment transpose (src lane = 32p+16mt+n)
  int bidx[2][2];
  #pragma unroll
  for (int p = 0; p < 2; p++)
    #pragma unroll
    for (int mt = 0; mt < 2; mt++) bidx[p][mt] = (32 * p + 16 * mt + n) << 2;

  __syncthreads();   // weights staged

  f16* hb = hbuf[wv];
  const int nsw = (n & 7) << 3;                        // XOR swizzle term (f16 units)

  for (int w = 0; w < NWIN; w++){
    const int wid = wslot * NWIN + w;
    const int b   = wid / (SS * (EE / WIN));
    const int rem = wid % (SS * (EE / WIN));
    const int s   = rem / (EE / WIN);
    const int e0  = (rem % (EE / WIN)) * WIN;

    const int* rows = row_idx + (size_t)(b * SS + s) * EE;
    const int* nbrs = nbr_idx + (size_t)(b * SS + s) * EE;
    const int rowbase = rows[e0];
    const size_t cofs    = (size_t)(b * SS + s) * MM + rowbase;
    const size_t outbase = ((size_t)b * MM + rowbase) * CC;

    // ---- zero per-wave accumulator ----
    #pragma unroll
    for (int i = 0; i < ACCR * CC / 64; i++) accs[wv][i * 64 + lane] = 0.f;

    // ---- prologue: gather mega-batch 0 into registers (t8 as 4 dwords) ----
    int tc0, tc1, tc2, tc3;
    {
      int f0 = e0 + lane;
      int row = rows[f0], nbr = nbrs[f0];
      float2 la = *(const float2*)(lat + row * 2);
      float2 xc = *(const float2*)(x_coord + ((size_t)b * NN + nbr) * 2);
      const float* pp = pndata + ((size_t)b * NN + nbr) * 3;
      tc0 = pk2(xc.x, xc.y);
      tc1 = pk2(la.x, la.y);
      tc2 = pk2(1.0f, pp[0]);
      tc3 = pk2(pp[1], pp[2]);
      rloc[wv][0][lane] = (ushort)(row - rowbase);
    }

    #pragma unroll
    for (int mb = 0; mb < 2; mb++){
      // ---- prefetch next mega-batch's gathers into registers ----
      int tn0 = 0, tn1 = 0, tn2 = 0, tn3 = 0;
      if (mb == 0){
        int f2 = e0 + 64 + lane;
        int row2 = rows[f2]; int nbr2 = nbrs[f2];
        float2 la2 = *(const float2*)(lat + row2 * 2);
        float2 xc2 = *(const float2*)(x_coord + ((size_t)b * NN + nbr2) * 2);
        const float* pp = pndata + ((size_t)b * NN + nbr2) * 3;
        tn0 = pk2(xc2.x, xc2.y);
        tn1 = pk2(la2.x, la2.y);
        tn2 = pk2(1.0f, pp[0]);
        tn3 = pk2(pp[1], pp[2]);
        rloc[wv][1][lane] = (ushort)(row2 - rowbase);
      }

      // ---- a1 frags via in-register transpose (ds_bpermute), no LDS staging ----
      f16x8 a1[2][2];
      #pragma unroll
      for (int p = 0; p < 2; p++)
        #pragma unroll
        for (int mt = 0; mt < 2; mt++){
          int d0 = __builtin_amdgcn_ds_bpermute(bidx[p][mt], tc0);
          int d1 = __builtin_amdgcn_ds_bpermute(bidx[p][mt], tc1);
          int d2 = __builtin_amdgcn_ds_bpermute(bidx[p][mt], tc2);
          int d3 = __builtin_amdgcn_ds_bpermute(bidx[p][mt], tc3);
          d0 = (g == 0) ? d0 : 0;
          d1 = (g == 0) ? d1 : 0;
          d2 = (g == 0) ? d2 : 0;
          d3 = (g == 0) ? d3 : 0;
          i32x4 dv = { d0, d1, d2, d3 };
          a1[p][mt] = __builtin_bit_cast(f16x8, dv);
        }

      // ---- layer 1, both tiles (swapped: D[j][edge] -> packed b64 writes) ----
      #pragma unroll
      for (int p = 0; p < 2; p++){
        f16* hbp = hb + p * 2048;
        #pragma unroll
        for (int jt = 0; jt < 4; jt++){
          #pragma unroll
          for (int et = 0; et < 2; et++){
            f32x4 d = __builtin_amdgcn_mfma_f32_16x16x32_f16(w1f[jt], a1[p][et], z4, 0, 0, 0);
            f16x4 pk = { (f16)gelu_tanh(d[0]), (f16)gelu_tanh(d[1]),
                         (f16)gelu_tanh(d[2]), (f16)gelu_tanh(d[3]) };
            *(f16x4*)(hbp + (16 * et + n) * 64 + ((16 * jt + 4 * g) ^ nsw)) = pk;
          }
        }
      }

      // ---- W2 A-frags (broadcast reads, shared by both tiles) ----
      f16x8 w2A[4][2];
      #pragma unroll
      for (int jt = 0; jt < 4; jt++)
        #pragma unroll
        for (int kt = 0; kt < 2; kt++)
          w2A[jt][kt] = *(const f16x8*)(w2lds + (16 * jt + n) * HH + ((32 * kt + 8 * g) ^ nsw));

      // ---- layer 2, both tiles (swapped) ----
      #pragma unroll
      for (int p = 0; p < 2; p++){
        f16* hbp = hb + p * 2048;
        f16x8 hB[2][2];
        #pragma unroll
        for (int et = 0; et < 2; et++)
          #pragma unroll
          for (int kt = 0; kt < 2; kt++)
            hB[et][kt] = *(const f16x8*)(hbp + (16 * et + n) * 64 + ((32 * kt + 8 * g) ^ nsw));
        #pragma unroll
        for (int jt = 0; jt < 4; jt++){
          #pragma unroll
          for (int et = 0; et < 2; et++){
            f32x4 d = __builtin_amdgcn_mfma_f32_16x16x32_f16(w2A[jt][0], hB[et][0], z4, 0, 0, 0);
            d = __builtin_amdgcn_mfma_f32_16x16x32_f16(w2A[jt][1], hB[et][1], d, 0, 0, 0);
            f16x4 pk = { (f16)gelu_tanh(d[0] + b2vv[jt].x), (f16)gelu_tanh(d[1] + b2vv[jt].y),
                         (f16)gelu_tanh(d[2] + b2vv[jt].z), (f16)gelu_tanh(d[3] + b2vv[jt].w) };
            *(f16x4*)(hbp + (16 * et + n) * 64 + ((16 * jt + 4 * g) ^ nsw)) = pk;
          }
        }
      }

      // ---- W3 B-frags (broadcast reads, shared) ----
      f16x8 w3B[2][2];   // [kt][ct]
      #pragma unroll
      for (int ct = 0; ct < 2; ct++)
        #pragma unroll
        for (int kt = 0; kt < 2; kt++)
          w3B[kt][ct] = *(const f16x8*)(w3lds + (16 * ct + n) * HH + ((32 * kt + 8 * g) ^ nsw));

      // ---- layer 3 (unswapped: D[edge][c]) + pv-MFMA + run-merged epilogue ----
      #pragma unroll
      for (int p = 0; p < 2; p++){
        f16* hbp = hb + p * 2048;
        #pragma unroll
        for (int mt = 0; mt < 2; mt++){
          int rw = 16 * mt + n;
          f16x8 a3k0 = *(const f16x8*)(hbp + rw * 64 + ((     8 * g) ^ ((rw & 7) << 3)));
          f16x8 a3k1 = *(const f16x8*)(hbp + rw * 64 + ((32 + 8 * g) ^ ((rw & 7) << 3)));
          f32x4 d0 = __builtin_amdgcn_mfma_f32_16x16x32_f16(a3k0, w3B[0][0], z4, 0, 0, 0);
          d0 = __builtin_amdgcn_mfma_f32_16x16x32_f16(a3k1, w3B[1][0], d0, 0, 0, 0);
          f32x4 d1 = __builtin_amdgcn_mfma_f32_16x16x32_f16(a3k0, w3B[0][1], z4, 0, 0, 0);
          d1 = __builtin_amdgcn_mfma_f32_16x16x32_f16(a3k1, w3B[1][1], d1, 0, 0, 0);
          f32x4 pv0 = __builtin_amdgcn_mfma_f32_16x16x32_f16(a1[p][mt], wlf[0], z4, 0, 0, 0);
          f32x4 pv1 = __builtin_amdgcn_mfma_f32_16x16x32_f16(a1[p][mt], wlf[1], z4, 0, 0, 0);

          uint2 rr = *(const uint2*)&rloc[wv][mb][32 * p + 16 * mt + 4 * g];
          int rl[4] = { (int)(rr.x & 0xffff), (int)(rr.x >> 16),
                        (int)(rr.y & 0xffff), (int)(rr.y >> 16) };
          float c0[4], c1[4];
          #pragma unroll
          for (int r = 0; r < 4; r++){
            c0[r] = (d0[r] + b3v[0]) * pv0[r];
            c1[r] = (d1[r] + b3v[1]) * pv1[r];
          }

          auto emitf = [&](int rl_, float s0_, float s1_){
            if (rl_ < ACCR){
              unsafeAtomicAdd(&accs[wv][rl_ * CC + n], s0_);
              unsafeAtomicAdd(&accs[wv][rl_ * CC + 16 + n], s1_);
            } else {
              float cf = coefw[cofs + rl_];
              unsafeAtomicAdd(out + outbase + (size_t)rl_ * CC + n, s0_ * cf);
              unsafeAtomicAdd(out + outbase + (size_t)rl_ * CC + 16 + n, s1_ * cf);
            }
          };

          int crl = rl[0]; float s0 = c0[0], s1 = c1[0];
          #pragma unroll
          for (int r = 1; r < 4; r++){
            if (rl[r] == crl){ s0 += c0[r]; s1 += c1[r]; }
            else { emitf(crl, s0, s1); crl = rl[r]; s0 = c0[r]; s1 = c1[r]; }
          }
          emitf(crl, s0, s1);
        }
      }

      // rotate prefetched mega-batch into current
      tc0 = tn0; tc1 = tn1; tc2 = tn2; tc3 = tn3;
    }

    // ---- flush wave accumulator (coef-weighted) ----
    const float* cfb = coefw + cofs;
    #pragma unroll
    for (int i = 0; i < ACCR * CC / 64; i++){
      int idx = i * 64 + lane;
      float v = accs[wv][idx];
      if (v != 0.f){
        int r = idx >> 5, ch = idx & 31;
        unsafeAtomicAdd(out + outbase + r * CC + ch, v * cfb[r]);
      }
    }
  }
}

extern "C" void kernel_launch(void* const* d_in, const int* in_sizes, int n_in,
                              void* d_out, int out_size, void* d_ws, size_t ws_size,
                              hipStream_t stream)
{
  const float* x_coord = (const float*)d_in[0];
  const float* pndata  = (const float*)d_in[1];
  const float* lat     = (const float*)d_in[2];
  const int*   nbr_idx = (const int*)d_in[3];
  const int*   row_idx = (const int*)d_in[4];
  const float* W_lift  = (const float*)d_in[5];
  const float* b_lift  = (const float*)d_in[6];
  const float* W1      = (const float*)d_in[7];
  const float* b1      = (const float*)d_in[8];
  const float* W2      = (const float*)d_in[9];
  const float* b2      = (const float*)d_in[10];
  const float* W3      = (const float*)d_in[11];
  const float* b3      = (const float*)d_in[12];
  const float* Ws1     = (const float*)d_in[13];
  const float* bs1     = (const float*)d_in[14];
  const float* Ws2     = (const float*)d_in[15];
  const float* bs2     = (const float*)d_in[16];
  float* out = (float*)d_out;

  // ws layout: W2h 8KB | W3h 4KB | W1p 1KB | WLp 0.5KB | pad | coef 384KB
  f16*   W2h   = (f16*)d_ws;
  f16*   W3h   = (f16*)((char*)d_ws + 8192);
  f16*   W1p   = (f16*)((char*)d_ws + 12288);
  f16*   WLp   = (f16*)((char*)d_ws + 13312);
  float* coefw = (float*)((char*)d_ws + 16384);

  hipMemsetAsync(d_out, 0, (size_t)out_size * sizeof(float), stream);
  hipLaunchKernelGGL(magno_pack, dim3(16), dim3(256), 0, stream,
                     W1, b1, W2, W3, W_lift, b_lift, W1p, W2h, W3h, WLp);
  hipLaunchKernelGGL(magno_coef, dim3((BB * SS * MM + 255) / 256), dim3(256), 0, stream,
                     lat, row_idx, Ws1, bs1, Ws2, bs2, coefw);
  hipLaunchKernelGGL(magno_main, dim3(BB * SS * (EE / WIN) / WPB / NWIN), dim3(TPB), 0, stream,
                     x_coord, pndata, lat, nbr_idx, row_idx,
                     b2, b3, W1p, W2h, W3h, WLp, coefw, out);
}

// Round 14
// 184.179 us; speedup vs baseline: 1.0301x; 1.0301x over previous
//
#include <hip/hip_runtime.h>
#include <stdint.h>

#define BB  2
#define NN  100000
#define MM  16384
#define SS  3
#define EE  262144
#define CC  32
#define HH  64
#define TPB 256
#define WPB 4            // waves per block
#define WIN 128          // edges per window
#define NWIN 3           // windows per wave (12288 / (1024*4))
#define ACCR 16          // accumulator rows per wave

typedef _Float16 f16;
typedef _Float16 f16x4 __attribute__((ext_vector_type(4)));
typedef _Float16 f16x8 __attribute__((ext_vector_type(8)));
typedef float    f32x4 __attribute__((ext_vector_type(4)));

// gelu = x * (1 - 1/(1 + 2^(K1*x + K3*x^3)))  (exact tanh-gelu reformulation)
__device__ __forceinline__ float gelu_tanh(float x){
  float u = x * fmaf(0.10294232f, x * x, 2.30218762f);
  float e = exp2f(u);
  float r = __builtin_amdgcn_rcpf(e + 1.0f);
  return fmaf(-x, r, x);
}

// ---- pack: f16 W1(+b1, K=8 pad), W2, W3, W_lift(+b_lift at k=4..7) ----
extern "C" __global__ void magno_pack(const float* __restrict__ W1, const float* __restrict__ b1,
                                      const float* __restrict__ W2, const float* __restrict__ W3,
                                      const float* __restrict__ W_lift, const float* __restrict__ b_lift,
                                      f16* __restrict__ W1p, f16* __restrict__ W2h,
                                      f16* __restrict__ W3h, f16* __restrict__ WLp){
  int i = blockIdx.x * blockDim.x + threadIdx.x;
  if (i < HH * HH) W2h[i] = (f16)W2[i];
  if (i < CC * HH) W3h[i] = (f16)W3[i];
  if (i < HH * 8){
    int j = i >> 3, k = i & 7;
    float v = (k < 4) ? W1[j * 4 + k] : (k == 4 ? b1[j] : 0.f);
    W1p[i] = (f16)v;
  }
  if (i < CC * 8){
    int c = i >> 3, k = i & 7;
    float v = (k == 4) ? b_lift[c] : (k >= 5 ? W_lift[c * 3 + (k - 5)] : 0.f);
    WLp[i] = (f16)v;
  }
}

// ---- coef[b,s,m] = softmax_s(scaleMLP(lat_m)) / max(cnt,1) ----
extern "C" __global__ void magno_coef(const float* __restrict__ lat, const int* __restrict__ row_idx,
                                      const float* __restrict__ Ws1, const float* __restrict__ bs1,
                                      const float* __restrict__ Ws2, const float* __restrict__ bs2,
                                      float* __restrict__ coefw){
  int idx = blockIdx.x * blockDim.x + threadIdx.x;
  if (idx >= BB * SS * MM) return;
  int m = idx % MM, s = (idx / MM) % SS, b = idx / (SS * MM);
  const int* rows = row_idx + (size_t)(b * SS + s) * EE;
  int lo = 0, hi = EE;
  while (lo < hi){ int mid = (lo + hi) >> 1; if (rows[mid] < m) lo = mid + 1; else hi = mid; }
  int l0 = lo; hi = EE;
  while (lo < hi){ int mid = (lo + hi) >> 1; if (rows[mid] < m + 1) lo = mid + 1; else hi = mid; }
  float cnt = (float)(lo - l0);
  float la = lat[m * 2 + 0], lb = lat[m * 2 + 1];
  float t[16];
  #pragma unroll
  for (int i = 0; i < 16; i++)
    t[i] = fmaxf(fmaf(la, Ws1[i * 2 + 0], fmaf(lb, Ws1[i * 2 + 1], bs1[i])), 0.f);
  float a0 = bs2[0], a1 = bs2[1], a2 = bs2[2];
  #pragma unroll
  for (int i = 0; i < 16; i++){
    a0 = fmaf(t[i], Ws2[i], a0); a1 = fmaf(t[i], Ws2[16 + i], a1); a2 = fmaf(t[i], Ws2[32 + i], a2);
  }
  float mx = fmaxf(a0, fmaxf(a1, a2));
  float e0 = __expf(a0 - mx), e1 = __expf(a1 - mx), e2 = __expf(a2 - mx);
  float inv = 1.f / (e0 + e1 + e2);
  float sw = (s == 0 ? e0 : (s == 1 ? e1 : e2)) * inv;
  coefw[idx] = sw / fmaxf(cnt, 1.f);
}

extern "C" __global__ void __launch_bounds__(TPB, 2)
magno_main(const float* __restrict__ x_coord,
           const float* __restrict__ pndata,
           const float* __restrict__ lat,
           const int* __restrict__ nbr_idx,
           const int* __restrict__ row_idx,
           const float* __restrict__ b2,
           const float* __restrict__ b3,
           const f16* __restrict__ W1p,
           const f16* __restrict__ W2h,
           const f16* __restrict__ W3h,
           const f16* __restrict__ WLp,
           const float* __restrict__ coefw,
           float* __restrict__ out)
{
  __shared__ __align__(16) f16   hbuf[WPB][64 * 64];   // TWO 32-edge pipeline tiles   32KB
  __shared__ __align__(16) f16   tst [WPB][64 * 8];    // staged t-vectors              4KB
  __shared__ ushort rloc[WPB][2][64];                  // local row per edge            1KB
  __shared__ float  accs[WPB][ACCR * CC];              // per-wave accumulators         8KB
  __shared__ __align__(16) f16   w2lds[HH * HH];       // W2 frags (XOR-swizzled)       8KB
  __shared__ __align__(16) f16   w3lds[CC * HH];       // W3 frags (XOR-swizzled)       4KB

  const int tid  = threadIdx.x;
  const int wv   = tid >> 6;
  const int lane = tid & 63;
  const int g    = lane >> 4;
  const int n    = lane & 15;
  const int wslot = blockIdx.x * WPB + wv;

  const f16x8 zf = {0,0,0,0,0,0,0,0};
  const f32x4 z4 = {0.f,0.f,0.f,0.f};

  // ---- stage W2/W3 into block LDS with XOR swizzle (col ^= (row&7)<<3, f16 units) ----
  for (int c = tid; c < 512; c += TPB){
    int row = c >> 3, cb = (c & 7) * 8;
    f16x8 v = *(const f16x8*)(W2h + row * HH + cb);
    *(f16x8*)(w2lds + row * HH + (cb ^ ((row & 7) << 3))) = v;
  }
  for (int c = tid; c < 256; c += TPB){
    int row = c >> 3, cb = (c & 7) * 8;
    f16x8 v = *(const f16x8*)(W3h + row * HH + cb);
    *(f16x8*)(w3lds + row * HH + (cb ^ ((row & 7) << 3))) = v;
  }

  // ---- register-resident small weights ----
  f16x8 w1f[4], wlf[2];
  #pragma unroll
  for (int nt = 0; nt < 4; nt++){
    f16x8 v = *(const f16x8*)(W1p + (16 * nt + n) * 8);
    w1f[nt] = (g == 0) ? v : zf;
  }
  #pragma unroll
  for (int nt = 0; nt < 2; nt++){
    f16x8 v = *(const f16x8*)(WLp + (16 * nt + n) * 8);
    wlf[nt] = (g == 0) ? v : zf;
  }
  // bias C-operands: l2 (swapped, row j = 16jt+4g+r): cb2[jt][r] = b2[16jt+4g+r]
  f32x4 cb2[4];
  #pragma unroll
  for (int jt = 0; jt < 4; jt++){
    float4 t = *(const float4*)(b2 + 16 * jt + 4 * g);
    cb2[jt] = (f32x4){ t.x, t.y, t.z, t.w };
  }
  // l3 (unswapped, col c = 16ct+n): cb3[ct] = splat(b3[16ct+n])
  f32x4 cb3[2];
  #pragma unroll
  for (int ct = 0; ct < 2; ct++){
    float v = b3[16 * ct + n];
    cb3[ct] = (f32x4){ v, v, v, v };
  }

  __syncthreads();   // weights staged

  f16* hb = hbuf[wv];
  f16* ts = tst[wv];
  const int nsw = (n & 7) << 3;                        // XOR swizzle term (f16 units)

  for (int w = 0; w < NWIN; w++){
    const int wid = wslot * NWIN + w;
    const int b   = wid / (SS * (EE / WIN));
    const int rem = wid % (SS * (EE / WIN));
    const int s   = rem / (EE / WIN);
    const int e0  = (rem % (EE / WIN)) * WIN;

    const int* rows = row_idx + (size_t)(b * SS + s) * EE;
    const int* nbrs = nbr_idx + (size_t)(b * SS + s) * EE;
    const int rowbase = rows[e0];
    const size_t cofs    = (size_t)(b * SS + s) * MM + rowbase;
    const size_t outbase = ((size_t)b * MM + rowbase) * CC;

    // ---- zero per-wave accumulator ----
    #pragma unroll
    for (int i = 0; i < ACCR * CC / 64; i++) accs[wv][i * 64 + lane] = 0.f;

    // ---- prologue: stage mega-batch 0 ----
    {
      int f0 = e0 + lane;
      int row = rows[f0], nbr = nbrs[f0];
      float2 la = *(const float2*)(lat + row * 2);
      float2 xc = *(const float2*)(x_coord + ((size_t)b * NN + nbr) * 2);
      const float* pp = pndata + ((size_t)b * NN + nbr) * 3;
      float p0 = pp[0], p1 = pp[1], p2 = pp[2];
      f16x8 t8 = {(f16)xc.x, (f16)xc.y, (f16)la.x, (f16)la.y, (f16)1.0f, (f16)p0, (f16)p1, (f16)p2};
      *(f16x8*)(ts + lane * 8) = t8;
      rloc[wv][0][lane] = (ushort)(row - rowbase);
    }

    #pragma unroll
    for (int mb = 0; mb < 2; mb++){
      // ---- prefetch next mega-batch's gathers ----
      int row2 = 0; float2 la2 = {0.f,0.f}, xc2 = {0.f,0.f};
      float q0 = 0.f, q1 = 0.f, q2 = 0.f;
      if (mb == 0){
        int f2 = e0 + 64 + lane;
        row2 = rows[f2]; int nbr2 = nbrs[f2];
        la2 = *(const float2*)(lat + row2 * 2);
        xc2 = *(const float2*)(x_coord + ((size_t)b * NN + nbr2) * 2);
        const float* pp = pndata + ((size_t)b * NN + nbr2) * 3;
        q0 = pp[0]; q1 = pp[1]; q2 = pp[2];
      }

      // ---- t8 frags for both pipeline tiles (A-frag for pv / B-frag for swapped l1) ----
      f16x8 a1[2][2];
      #pragma unroll
      for (int p = 0; p < 2; p++)
        #pragma unroll
        for (int mt = 0; mt < 2; mt++){
          f16x8 v = *(const f16x8*)(ts + (32 * p + 16 * mt + n) * 8);
          a1[p][mt] = (g == 0) ? v : zf;
        }

      // after the LAST read of tst, stage the prefetched mega-batch
      if (mb == 0){
        f16x8 t8 = {(f16)xc2.x, (f16)xc2.y, (f16)la2.x, (f16)la2.y, (f16)1.0f, (f16)q0, (f16)q1, (f16)q2};
        *(f16x8*)(ts + lane * 8) = t8;
        rloc[wv][1][lane] = (ushort)(row2 - rowbase);
      }

      // ---- layer 1, both tiles (swapped: D[j][edge] -> packed b64 writes) ----
      #pragma unroll
      for (int p = 0; p < 2; p++){
        f16* hbp = hb + p * 2048;
        #pragma unroll
        for (int jt = 0; jt < 4; jt++){
          #pragma unroll
          for (int et = 0; et < 2; et++){
            f32x4 d = __builtin_amdgcn_mfma_f32_16x16x32_f16(w1f[jt], a1[p][et], z4, 0, 0, 0);
            f16x4 pk = { (f16)gelu_tanh(d[0]), (f16)gelu_tanh(d[1]),
                         (f16)gelu_tanh(d[2]), (f16)gelu_tanh(d[3]) };
            *(f16x4*)(hbp + (16 * et + n) * 64 + ((16 * jt + 4 * g) ^ nsw)) = pk;
          }
        }
      }

      // ---- W2 A-frags (broadcast reads, shared by both tiles) ----
      f16x8 w2A[4][2];
      #pragma unroll
      for (int jt = 0; jt < 4; jt++)
        #pragma unroll
        for (int kt = 0; kt < 2; kt++)
          w2A[jt][kt] = *(const f16x8*)(w2lds + (16 * jt + n) * HH + ((32 * kt + 8 * g) ^ nsw));

      // ---- layer 2, both tiles (swapped; bias folded into MFMA C) ----
      #pragma unroll
      for (int p = 0; p < 2; p++){
        f16* hbp = hb + p * 2048;
        f16x8 hB[2][2];
        #pragma unroll
        for (int et = 0; et < 2; et++)
          #pragma unroll
          for (int kt = 0; kt < 2; kt++)
            hB[et][kt] = *(const f16x8*)(hbp + (16 * et + n) * 64 + ((32 * kt + 8 * g) ^ nsw));
        #pragma unroll
        for (int jt = 0; jt < 4; jt++){
          #pragma unroll
          for (int et = 0; et < 2; et++){
            f32x4 d = __builtin_amdgcn_mfma_f32_16x16x32_f16(w2A[jt][0], hB[et][0], cb2[jt], 0, 0, 0);
            d = __builtin_amdgcn_mfma_f32_16x16x32_f16(w2A[jt][1], hB[et][1], d, 0, 0, 0);
            f16x4 pk = { (f16)gelu_tanh(d[0]), (f16)gelu_tanh(d[1]),
                         (f16)gelu_tanh(d[2]), (f16)gelu_tanh(d[3]) };
            *(f16x4*)(hbp + (16 * et + n) * 64 + ((16 * jt + 4 * g) ^ nsw)) = pk;
          }
        }
      }

      // ---- W3 B-frags (broadcast reads, shared) ----
      f16x8 w3B[2][2];   // [kt][ct]
      #pragma unroll
      for (int ct = 0; ct < 2; ct++)
        #pragma unroll
        for (int kt = 0; kt < 2; kt++)
          w3B[kt][ct] = *(const f16x8*)(w3lds + (16 * ct + n) * HH + ((32 * kt + 8 * g) ^ nsw));

      // ---- layer 3 (unswapped; b3 folded into C) + pv-MFMA + run-merged epilogue ----
      #pragma unroll
      for (int p = 0; p < 2; p++){
        f16* hbp = hb + p * 2048;
        #pragma unroll
        for (int mt = 0; mt < 2; mt++){
          int rw = 16 * mt + n;
          f16x8 a3k0 = *(const f16x8*)(hbp + rw * 64 + ((     8 * g) ^ ((rw & 7) << 3)));
          f16x8 a3k1 = *(const f16x8*)(hbp + rw * 64 + ((32 + 8 * g) ^ ((rw & 7) << 3)));
          f32x4 d0 = __builtin_amdgcn_mfma_f32_16x16x32_f16(a3k0, w3B[0][0], cb3[0], 0, 0, 0);
          d0 = __builtin_amdgcn_mfma_f32_16x16x32_f16(a3k1, w3B[1][0], d0, 0, 0, 0);
          f32x4 d1 = __builtin_amdgcn_mfma_f32_16x16x32_f16(a3k0, w3B[0][1], cb3[1], 0, 0, 0);
          d1 = __builtin_amdgcn_mfma_f32_16x16x32_f16(a3k1, w3B[1][1], d1, 0, 0, 0);
          f32x4 pv0 = __builtin_amdgcn_mfma_f32_16x16x32_f16(a1[p][mt], wlf[0], z4, 0, 0, 0);
          f32x4 pv1 = __builtin_amdgcn_mfma_f32_16x16x32_f16(a1[p][mt], wlf[1], z4, 0, 0, 0);

          uint2 rr = *(const uint2*)&rloc[wv][mb][32 * p + 16 * mt + 4 * g];
          int rl[4] = { (int)(rr.x & 0xffff), (int)(rr.x >> 16),
                        (int)(rr.y & 0xffff), (int)(rr.y >> 16) };
          float c0[4], c1[4];
          #pragma unroll
          for (int r = 0; r < 4; r++){
            c0[r] = d0[r] * pv0[r];
            c1[r] = d1[r] * pv1[r];
          }

          auto emitf = [&](int rl_, float s0_, float s1_){
            if (rl_ < ACCR){
              unsafeAtomicAdd(&accs[wv][rl_ * CC + n], s0_);
              unsafeAtomicAdd(&accs[wv][rl_ * CC + 16 + n], s1_);
            } else {
              float cf = coefw[cofs + rl_];
              unsafeAtomicAdd(out + outbase + (size_t)rl_ * CC + n, s0_ * cf);
              unsafeAtomicAdd(out + outbase + (size_t)rl_ * CC + 16 + n, s1_ * cf);
            }
          };

          int crl = rl[0]; float s0 = c0[0], s1 = c1[0];
          #pragma unroll
          for (int r = 1; r < 4; r++){
            if (rl[r] == crl){ s0 += c0[r]; s1 += c1[r]; }
            else { emitf(crl, s0, s1); crl = rl[r]; s0 = c0[r]; s1 = c1[r]; }
          }
          emitf(crl, s0, s1);
        }
      }
    }

    // ---- flush wave accumulator (coef-weighted) ----
    const float* cfb = coefw + cofs;
    #pragma unroll
    for (int i = 0; i < ACCR * CC / 64; i++){
      int idx = i * 64 + lane;
      float v = accs[wv][idx];
      if (v != 0.f){
        int r = idx >> 5, ch = idx & 31;
        unsafeAtomicAdd(out + outbase + r * CC + ch, v * cfb[r]);
      }
    }
  }
}

extern "C" void kernel_launch(void* const* d_in, const int* in_sizes, int n_in,
                              void* d_out, int out_size, void* d_ws, size_t ws_size,
                              hipStream_t stream)
{
  const float* x_coord = (const float*)d_in[0];
  const float* pndata  = (const float*)d_in[1];
  const float* lat     = (const float*)d_in[2];
  const int*   nbr_idx = (const int*)d_in[3];
  const int*   row_idx = (const int*)d_in[4];
  const float* W_lift  = (const float*)d_in[5];
  const float* b_lift  = (const float*)d_in[6];
  const float* W1      = (const float*)d_in[7];
  const float* b1      = (const float*)d_in[8];
  const float* W2      = (const float*)d_in[9];
  const float* b2      = (const float*)d_in[10];
  const float* W3      = (const float*)d_in[11];
  const float* b3      = (const float*)d_in[12];
  const float* Ws1     = (const float*)d_in[13];
  const float* bs1     = (const float*)d_in[14];
  const float* Ws2     = (const float*)d_in[15];
  const float* bs2     = (const float*)d_in[16];
  float* out = (float*)d_out;

  // ws layout: W2h 8KB | W3h 4KB | W1p 1KB | WLp 0.5KB | pad | coef 384KB
  f16*   W2h   = (f16*)d_ws;
  f16*   W3h   = (f16*)((char*)d_ws + 8192);
  f16*   W1p   = (f16*)((char*)d_ws + 12288);
  f16*   WLp   = (f16*)((char*)d_ws + 13312);
  float* coefw = (float*)((char*)d_ws + 16384);

  hipMemsetAsync(d_out, 0, (size_t)out_size * sizeof(float), stream);
  hipLaunchKernelGGL(magno_pack, dim3(16), dim3(256), 0, stream,
                     W1, b1, W2, W3, W_lift, b_lift, W1p, W2h, W3h, WLp);
  hipLaunchKernelGGL(magno_coef, dim3((BB * SS * MM + 255) / 256), dim3(256), 0, stream,
                     lat, row_idx, Ws1, bs1, Ws2, bs2, coefw);
  hipLaunchKernelGGL(magno_main, dim3(BB * SS * (EE / WIN) / WPB / NWIN), dim3(TPB), 0, stream,
                     x_coord, pndata, lat, nbr_idx, row_idx,
                     b2, b3, W1p, W2h, W3h, WLp, coefw, out);
}

// Round 15
// 171.520 us; speedup vs baseline: 1.1061x; 1.0738x over previous
//
#include <hip/hip_runtime.h>
#include <stdint.h>

#define BB  2
#define NN  100000
#define MM  16384
#define SS  3
#define EE  262144
#define CC  32
#define HH  64
#define TPB 256
#define WPB 4            // waves per block
#define WIN 128          // edges per window
#define NWIN 4           // windows per wave (12288 / (768*4))
#define ACCR 16          // accumulator rows per wave

typedef _Float16 f16;
typedef _Float16 f16x4 __attribute__((ext_vector_type(4)));
typedef _Float16 f16x8 __attribute__((ext_vector_type(8)));
typedef float    f32x4 __attribute__((ext_vector_type(4)));

// gelu = x * (1 - 1/(1 + 2^(K1*x + K3*x^3)))  (exact tanh-gelu reformulation)
__device__ __forceinline__ float gelu_tanh(float x){
  float u = x * fmaf(0.10294232f, x * x, 2.30218762f);
  float e = exp2f(u);
  float r = __builtin_amdgcn_rcpf(e + 1.0f);
  return fmaf(-x, r, x);
}

// ---- pack: f16 W1(+b1, K=8 pad), W2, W3, W_lift(+b_lift at k=4..7) ----
extern "C" __global__ void magno_pack(const float* __restrict__ W1, const float* __restrict__ b1,
                                      const float* __restrict__ W2, const float* __restrict__ W3,
                                      const float* __restrict__ W_lift, const float* __restrict__ b_lift,
                                      f16* __restrict__ W1p, f16* __restrict__ W2h,
                                      f16* __restrict__ W3h, f16* __restrict__ WLp){
  int i = blockIdx.x * blockDim.x + threadIdx.x;
  if (i < HH * HH) W2h[i] = (f16)W2[i];
  if (i < CC * HH) W3h[i] = (f16)W3[i];
  if (i < HH * 8){
    int j = i >> 3, k = i & 7;
    float v = (k < 4) ? W1[j * 4 + k] : (k == 4 ? b1[j] : 0.f);
    W1p[i] = (f16)v;
  }
  if (i < CC * 8){
    int c = i >> 3, k = i & 7;
    float v = (k == 4) ? b_lift[c] : (k >= 5 ? W_lift[c * 3 + (k - 5)] : 0.f);
    WLp[i] = (f16)v;
  }
}

// ---- coef[b,s,m] = softmax_s(scaleMLP(lat_m)) / max(cnt,1) ----
extern "C" __global__ void magno_coef(const float* __restrict__ lat, const int* __restrict__ row_idx,
                                      const float* __restrict__ Ws1, const float* __restrict__ bs1,
                                      const float* __restrict__ Ws2, const float* __restrict__ bs2,
                                      float* __restrict__ coefw){
  int idx = blockIdx.x * blockDim.x + threadIdx.x;
  if (idx >= BB * SS * MM) return;
  int m = idx % MM, s = (idx / MM) % SS, b = idx / (SS * MM);
  const int* rows = row_idx + (size_t)(b * SS + s) * EE;
  int lo = 0, hi = EE;
  while (lo < hi){ int mid = (lo + hi) >> 1; if (rows[mid] < m) lo = mid + 1; else hi = mid; }
  int l0 = lo; hi = EE;
  while (lo < hi){ int mid = (lo + hi) >> 1; if (rows[mid] < m + 1) lo = mid + 1; else hi = mid; }
  float cnt = (float)(lo - l0);
  float la = lat[m * 2 + 0], lb = lat[m * 2 + 1];
  float t[16];
  #pragma unroll
  for (int i = 0; i < 16; i++)
    t[i] = fmaxf(fmaf(la, Ws1[i * 2 + 0], fmaf(lb, Ws1[i * 2 + 1], bs1[i])), 0.f);
  float a0 = bs2[0], a1 = bs2[1], a2 = bs2[2];
  #pragma unroll
  for (int i = 0; i < 16; i++){
    a0 = fmaf(t[i], Ws2[i], a0); a1 = fmaf(t[i], Ws2[16 + i], a1); a2 = fmaf(t[i], Ws2[32 + i], a2);
  }
  float mx = fmaxf(a0, fmaxf(a1, a2));
  float e0 = __expf(a0 - mx), e1 = __expf(a1 - mx), e2 = __expf(a2 - mx);
  float inv = 1.f / (e0 + e1 + e2);
  float sw = (s == 0 ? e0 : (s == 1 ? e1 : e2)) * inv;
  coefw[idx] = sw / fmaxf(cnt, 1.f);
}

extern "C" __global__ void __launch_bounds__(TPB, 3)
magno_main(const float* __restrict__ x_coord,
           const float* __restrict__ pndata,
           const float* __restrict__ lat,
           const int* __restrict__ nbr_idx,
           const int* __restrict__ row_idx,
           const float* __restrict__ b2,
           const float* __restrict__ b3,
           const f16* __restrict__ W1p,
           const f16* __restrict__ W2h,
           const f16* __restrict__ W3h,
           const f16* __restrict__ WLp,
           const float* __restrict__ coefw,
           float* __restrict__ out)
{
  __shared__ __align__(16) f16   hbuf[WPB][32 * 64];   // ONE 32-edge tile per wave    16KB
  __shared__ __align__(16) f16   tst [WPB][64 * 8];    // staged t-vectors              4KB
  __shared__ ushort rloc[WPB][2][64];                  // local row per edge            1KB
  __shared__ float  accs[WPB][ACCR * CC];              // per-wave accumulators         8KB
  __shared__ __align__(16) f16   w2lds[HH * HH];       // W2 frags (XOR-swizzled)       8KB
  __shared__ __align__(16) f16   w3lds[CC * HH];       // W3 frags (XOR-swizzled)       4KB
  // total 41984 B -> 3 blocks/CU at 3 waves/EU

  const int tid  = threadIdx.x;
  const int wv   = tid >> 6;
  const int lane = tid & 63;
  const int g    = lane >> 4;
  const int n    = lane & 15;
  const int wslot = blockIdx.x * WPB + wv;

  const f16x8 zf = {0,0,0,0,0,0,0,0};
  const f32x4 z4 = {0.f,0.f,0.f,0.f};

  // ---- stage W2/W3 into block LDS with XOR swizzle (col ^= (row&7)<<3, f16 units) ----
  for (int c = tid; c < 512; c += TPB){
    int row = c >> 3, cb = (c & 7) * 8;
    f16x8 v = *(const f16x8*)(W2h + row * HH + cb);
    *(f16x8*)(w2lds + row * HH + (cb ^ ((row & 7) << 3))) = v;
  }
  for (int c = tid; c < 256; c += TPB){
    int row = c >> 3, cb = (c & 7) * 8;
    f16x8 v = *(const f16x8*)(W3h + row * HH + cb);
    *(f16x8*)(w3lds + row * HH + (cb ^ ((row & 7) << 3))) = v;
  }

  // ---- register-resident small weights ----
  f16x8 w1f[4], wlf[2];
  #pragma unroll
  for (int nt = 0; nt < 4; nt++){
    f16x8 v = *(const f16x8*)(W1p + (16 * nt + n) * 8);
    w1f[nt] = (g == 0) ? v : zf;
  }
  #pragma unroll
  for (int nt = 0; nt < 2; nt++){
    f16x8 v = *(const f16x8*)(WLp + (16 * nt + n) * 8);
    wlf[nt] = (g == 0) ? v : zf;
  }
  // bias C-operands
  f32x4 cb2[4];
  #pragma unroll
  for (int jt = 0; jt < 4; jt++){
    float4 t = *(const float4*)(b2 + 16 * jt + 4 * g);
    cb2[jt] = (f32x4){ t.x, t.y, t.z, t.w };
  }
  f32x4 cb3[2];
  #pragma unroll
  for (int ct = 0; ct < 2; ct++){
    float v = b3[16 * ct + n];
    cb3[ct] = (f32x4){ v, v, v, v };
  }

  __syncthreads();   // weights staged

  f16* hb = hbuf[wv];
  f16* ts = tst[wv];
  const int nsw = (n & 7) << 3;                        // XOR swizzle term (f16 units)

  for (int w = 0; w < NWIN; w++){
    const int wid = wslot * NWIN + w;
    const int b   = wid / (SS * (EE / WIN));
    const int rem = wid % (SS * (EE / WIN));
    const int s   = rem / (EE / WIN);
    const int e0  = (rem % (EE / WIN)) * WIN;

    const int* rows = row_idx + (size_t)(b * SS + s) * EE;
    const int* nbrs = nbr_idx + (size_t)(b * SS + s) * EE;
    const int rowbase = rows[e0];
    const size_t cofs    = (size_t)(b * SS + s) * MM + rowbase;
    const size_t outbase = ((size_t)b * MM + rowbase) * CC;

    // ---- zero per-wave accumulator ----
    #pragma unroll
    for (int i = 0; i < ACCR * CC / 64; i++) accs[wv][i * 64 + lane] = 0.f;

    // ---- prologue: stage mega-batch 0 ----
    {
      int f0 = e0 + lane;
      int row = rows[f0], nbr = nbrs[f0];
      float2 la = *(const float2*)(lat + row * 2);
      float2 xc = *(const float2*)(x_coord + ((size_t)b * NN + nbr) * 2);
      const float* pp = pndata + ((size_t)b * NN + nbr) * 3;
      float p0 = pp[0], p1 = pp[1], p2 = pp[2];
      f16x8 t8 = {(f16)xc.x, (f16)xc.y, (f16)la.x, (f16)la.y, (f16)1.0f, (f16)p0, (f16)p1, (f16)p2};
      *(f16x8*)(ts + lane * 8) = t8;
      rloc[wv][0][lane] = (ushort)(row - rowbase);
    }

    #pragma unroll
    for (int mb = 0; mb < 2; mb++){
      // ---- prefetch next mega-batch's gathers ----
      int row2 = 0; float2 la2 = {0.f,0.f}, xc2 = {0.f,0.f};
      float q0 = 0.f, q1 = 0.f, q2 = 0.f;
      if (mb == 0){
        int f2 = e0 + 64 + lane;
        row2 = rows[f2]; int nbr2 = nbrs[f2];
        la2 = *(const float2*)(lat + row2 * 2);
        xc2 = *(const float2*)(x_coord + ((size_t)b * NN + nbr2) * 2);
        const float* pp = pndata + ((size_t)b * NN + nbr2) * 3;
        q0 = pp[0]; q1 = pp[1]; q2 = pp[2];
      }

      // ---- two 32-edge tiles processed sequentially through the single hbuf ----
      #pragma unroll
      for (int p = 0; p < 2; p++){
        // t8 frags for this tile (A-frag for pv / B-frag for swapped l1)
        f16x8 a1[2];
        #pragma unroll
        for (int mt = 0; mt < 2; mt++){
          f16x8 v = *(const f16x8*)(ts + (32 * p + 16 * mt + n) * 8);
          a1[mt] = (g == 0) ? v : zf;
        }

        // after the LAST read of tst, stage the prefetched mega-batch
        if (mb == 0 && p == 1){
          f16x8 t8 = {(f16)xc2.x, (f16)xc2.y, (f16)la2.x, (f16)la2.y, (f16)1.0f, (f16)q0, (f16)q1, (f16)q2};
          *(f16x8*)(ts + lane * 8) = t8;
          rloc[wv][1][lane] = (ushort)(row2 - rowbase);
        }

        // ---- layer 1 (swapped: D[j][edge] -> packed b64 writes) ----
        #pragma unroll
        for (int jt = 0; jt < 4; jt++){
          #pragma unroll
          for (int et = 0; et < 2; et++){
            f32x4 d = __builtin_amdgcn_mfma_f32_16x16x32_f16(w1f[jt], a1[et], z4, 0, 0, 0);
            f16x4 pk = { (f16)gelu_tanh(d[0]), (f16)gelu_tanh(d[1]),
                         (f16)gelu_tanh(d[2]), (f16)gelu_tanh(d[3]) };
            *(f16x4*)(hb + (16 * et + n) * 64 + ((16 * jt + 4 * g) ^ nsw)) = pk;
          }
        }

        // ---- layer 2 (swapped; W2 frags loaded per-jt to bound reg pressure) ----
        f16x8 hB[2][2];
        #pragma unroll
        for (int et = 0; et < 2; et++)
          #pragma unroll
          for (int kt = 0; kt < 2; kt++)
            hB[et][kt] = *(const f16x8*)(hb + (16 * et + n) * 64 + ((32 * kt + 8 * g) ^ nsw));
        #pragma unroll
        for (int jt = 0; jt < 4; jt++){
          f16x8 wA0 = *(const f16x8*)(w2lds + (16 * jt + n) * HH + ((      8 * g) ^ nsw));
          f16x8 wA1 = *(const f16x8*)(w2lds + (16 * jt + n) * HH + ((32 + 8 * g) ^ nsw));
          #pragma unroll
          for (int et = 0; et < 2; et++){
            f32x4 d = __builtin_amdgcn_mfma_f32_16x16x32_f16(wA0, hB[et][0], cb2[jt], 0, 0, 0);
            d = __builtin_amdgcn_mfma_f32_16x16x32_f16(wA1, hB[et][1], d, 0, 0, 0);
            f16x4 pk = { (f16)gelu_tanh(d[0]), (f16)gelu_tanh(d[1]),
                         (f16)gelu_tanh(d[2]), (f16)gelu_tanh(d[3]) };
            *(f16x4*)(hb + (16 * et + n) * 64 + ((16 * jt + 4 * g) ^ nsw)) = pk;
          }
        }

        // ---- layer 3 (unswapped; W3 frags loaded just before use) + pv + epilogue ----
        #pragma unroll
        for (int mt = 0; mt < 2; mt++){
          int rw = 16 * mt + n;
          f16x8 a3k0 = *(const f16x8*)(hb + rw * 64 + ((     8 * g) ^ ((rw & 7) << 3)));
          f16x8 a3k1 = *(const f16x8*)(hb + rw * 64 + ((32 + 8 * g) ^ ((rw & 7) << 3)));
          f16x8 w300 = *(const f16x8*)(w3lds + (     n) * HH + ((      8 * g) ^ nsw));
          f16x8 w310 = *(const f16x8*)(w3lds + (     n) * HH + ((32 + 8 * g) ^ nsw));
          f16x8 w301 = *(const f16x8*)(w3lds + (16 + n) * HH + ((      8 * g) ^ nsw));
          f16x8 w311 = *(const f16x8*)(w3lds + (16 + n) * HH + ((32 + 8 * g) ^ nsw));
          f32x4 d0 = __builtin_amdgcn_mfma_f32_16x16x32_f16(a3k0, w300, cb3[0], 0, 0, 0);
          d0 = __builtin_amdgcn_mfma_f32_16x16x32_f16(a3k1, w310, d0, 0, 0, 0);
          f32x4 d1 = __builtin_amdgcn_mfma_f32_16x16x32_f16(a3k0, w301, cb3[1], 0, 0, 0);
          d1 = __builtin_amdgcn_mfma_f32_16x16x32_f16(a3k1, w311, d1, 0, 0, 0);
          f32x4 pv0 = __builtin_amdgcn_mfma_f32_16x16x32_f16(a1[mt], wlf[0], z4, 0, 0, 0);
          f32x4 pv1 = __builtin_amdgcn_mfma_f32_16x16x32_f16(a1[mt], wlf[1], z4, 0, 0, 0);

          uint2 rr = *(const uint2*)&rloc[wv][mb][32 * p + 16 * mt + 4 * g];
          int rl[4] = { (int)(rr.x & 0xffff), (int)(rr.x >> 16),
                        (int)(rr.y & 0xffff), (int)(rr.y >> 16) };
          float c0[4], c1[4];
          #pragma unroll
          for (int r = 0; r < 4; r++){
            c0[r] = d0[r] * pv0[r];
            c1[r] = d1[r] * pv1[r];
          }

          auto emitf = [&](int rl_, float s0_, float s1_){
            if (rl_ < ACCR){
              unsafeAtomicAdd(&accs[wv][rl_ * CC + n], s0_);
              unsafeAtomicAdd(&accs[wv][rl_ * CC + 16 + n], s1_);
            } else {
              float cf = coefw[cofs + rl_];
              unsafeAtomicAdd(out + outbase + (size_t)rl_ * CC + n, s0_ * cf);
              unsafeAtomicAdd(out + outbase + (size_t)rl_ * CC + 16 + n, s1_ * cf);
            }
          };

          int crl = rl[0]; float s0 = c0[0], s1 = c1[0];
          #pragma unroll
          for (int r = 1; r < 4; r++){
            if (rl[r] == crl){ s0 += c0[r]; s1 += c1[r]; }
            else { emitf(crl, s0, s1); crl = rl[r]; s0 = c0[r]; s1 = c1[r]; }
          }
          emitf(crl, s0, s1);
        }
      }
    }

    // ---- flush wave accumulator (coef-weighted) ----
    const float* cfb = coefw + cofs;
    #pragma unroll
    for (int i = 0; i < ACCR * CC / 64; i++){
      int idx = i * 64 + lane;
      float v = accs[wv][idx];
      if (v != 0.f){
        int r = idx >> 5, ch = idx & 31;
        unsafeAtomicAdd(out + outbase + r * CC + ch, v * cfb[r]);
      }
    }
  }
}

extern "C" void kernel_launch(void* const* d_in, const int* in_sizes, int n_in,
                              void* d_out, int out_size, void* d_ws, size_t ws_size,
                              hipStream_t stream)
{
  const float* x_coord = (const float*)d_in[0];
  const float* pndata  = (const float*)d_in[1];
  const float* lat     = (const float*)d_in[2];
  const int*   nbr_idx = (const int*)d_in[3];
  const int*   row_idx = (const int*)d_in[4];
  const float* W_lift  = (const float*)d_in[5];
  const float* b_lift  = (const float*)d_in[6];
  const float* W1      = (const float*)d_in[7];
  const float* b1      = (const float*)d_in[8];
  const float* W2      = (const float*)d_in[9];
  const float* b2      = (const float*)d_in[10];
  const float* W3      = (const float*)d_in[11];
  const float* b3      = (const float*)d_in[12];
  const float* Ws1     = (const float*)d_in[13];
  const float* bs1     = (const float*)d_in[14];
  const float* Ws2     = (const float*)d_in[15];
  const float* bs2     = (const float*)d_in[16];
  float* out = (float*)d_out;

  // ws layout: W2h 8KB | W3h 4KB | W1p 1KB | WLp 0.5KB | pad | coef 384KB
  f16*   W2h   = (f16*)d_ws;
  f16*   W3h   = (f16*)((char*)d_ws + 8192);
  f16*   W1p   = (f16*)((char*)d_ws + 12288);
  f16*   WLp   = (f16*)((char*)d_ws + 13312);
  float* coefw = (float*)((char*)d_ws + 16384);

  hipMemsetAsync(d_out, 0, (size_t)out_size * sizeof(float), stream);
  hipLaunchKernelGGL(magno_pack, dim3(16), dim3(256), 0, stream,
                     W1, b1, W2, W3, W_lift, b_lift, W1p, W2h, W3h, WLp);
  hipLaunchKernelGGL(magno_coef, dim3((BB * SS * MM + 255) / 256), dim3(256), 0, stream,
                     lat, row_idx, Ws1, bs1, Ws2, bs2, coefw);
  hipLaunchKernelGGL(magno_main, dim3(BB * SS * (EE / WIN) / WPB / NWIN), dim3(TPB), 0, stream,
                     x_coord, pndata, lat, nbr_idx, row_idx,
                     b2, b3, W1p, W2h, W3h, WLp, coefw, out);
}